// Round 3
// baseline (11769.321 us; speedup 1.0000x reference)
//
#include <hip/hip_runtime.h>
#include <stdint.h>

#define BATCH 8
#define NPTS 4096
#define KNN 20
#define NSPLIT 2
#define CAND_PER_SPLIT (NPTS / NSPLIT)   // 2048
#define TILE 64
#define CAP 16
#define KTHR 256                          // knn2 block size
constexpr float SLOPE = 0.2f;

typedef unsigned long long u64;
// hi word unpacks to FLT_MAX (0x7F7FFFFF) -- FINITE, so the tmax threshold
// stays permissive (not NaN!) until the list holds 20 real entries.
#define INIT_KEY 0xFF7FFFFFFFFFFFFFULL

// ---------------------------------------------------------------------------
// squared norms
// ---------------------------------------------------------------------------
template<int D>
__global__ __launch_bounds__(256) void sq_kernel(const float* __restrict__ X,
                                                 float* __restrict__ sq) {
    const int i = blockIdx.x * 256 + threadIdx.x;
    if constexpr (D == 3) {
        const float* p = X + (size_t)i * 3;
        float s = 0.f;
        s += p[0] * p[0]; s += p[1] * p[1]; s += p[2] * p[2];
        sq[i] = s;
    } else {
        const float4* p = (const float4*)(X + (size_t)i * 64);
        float s = 0.f;
        #pragma unroll
        for (int k = 0; k < 16; ++k) {
            float4 v = p[k];
            s += v.x * v.x; s += v.y * v.y; s += v.z * v.z; s += v.w * v.w;
        }
        sq[i] = s;
    }
}

// ---------------------------------------------------------------------------
// kNN: query-per-thread, LDS-broadcast candidate tiles, threshold+buffer
// selection (exact top-20 on packed (d,j) u64 keys, ties -> low j).
// grid: (NPTS/KTHR, NSPLIT, BATCH), KTHR threads.
// ---------------------------------------------------------------------------
__device__ __forceinline__ u64 pack_key(float d, int j) {
    unsigned ub = __float_as_uint(d);
    ub = (ub & 0x80000000u) ? ~ub : (ub | 0x80000000u);
    return ((u64)ub << 32) | (unsigned)j;
}
__device__ __forceinline__ float key_hi_to_d(unsigned hi) {
    unsigned u = (hi & 0x80000000u) ? (hi ^ 0x80000000u) : ~hi;
    return __uint_as_float(u);
}
__device__ __forceinline__ void insert_key(u64 (&lst)[KNN], u64 c) {
    #pragma unroll
    for (int k = 0; k < KNN; ++k) {
        const u64 lo = (lst[k] < c) ? lst[k] : c;
        const u64 hi = (lst[k] < c) ? c : lst[k];
        lst[k] = lo; c = hi;
    }
}
__device__ __forceinline__ void flush_buf(u64 (&lst)[KNN], const u64* __restrict__ buf,
                                          int t, int& cnt, float& tmax) {
    for (int i = 0; i < CAP; ++i) {
        if (i < cnt) {
            const u64 key = buf[i * KTHR + t];
            if (key < lst[KNN - 1]) insert_key(lst, key);
        }
    }
    cnt = 0;
    tmax = key_hi_to_d((unsigned)(lst[KNN - 1] >> 32));
}

template<int D>   // 3 or 64
__global__ __launch_bounds__(KTHR) void knn2_kernel(
    const float* __restrict__ X, const float* __restrict__ sq,
    u64* __restrict__ part)      // [NSPLIT][KNN][B*N]
{
    __shared__ alignas(16) float xt[TILE * ((D == 3) ? 3 : 64)];
    __shared__ float sqt[TILE];
    __shared__ u64 buf[CAP * KTHR];     // lane-interleaved: buf[i][t]

    const int t = threadIdx.x;
    const int split = blockIdx.y, b = blockIdx.z;
    const int q = blockIdx.x * KTHR + t;
    const float* Xb = X + (size_t)b * NPTS * D;
    const size_t BN = (size_t)BATCH * NPTS;

    float4 xq[(D == 3) ? 1 : 16];
    if constexpr (D == 3) {
        const float* qp = Xb + (size_t)q * 3;
        xq[0].x = qp[0]; xq[0].y = qp[1]; xq[0].z = qp[2]; xq[0].w = 0.f;
    } else {
        #pragma unroll
        for (int k = 0; k < 16; ++k)
            xq[k] = *(const float4*)&Xb[(size_t)q * 64 + 4 * k];
    }
    const float sqq = sq[(size_t)b * NPTS + q];

    u64 lst[KNN];
    #pragma unroll
    for (int k = 0; k < KNN; ++k) lst[k] = INIT_KEY;
    float tmax = 3.402823466e38f;   // FLT_MAX: pass everything until list full
    int cnt = 0;

    for (int tile = 0; tile < CAND_PER_SPLIT / TILE; ++tile) {
        const int cbase = split * CAND_PER_SPLIT + tile * TILE;
        // ---- stage candidate tile
        if constexpr (D == 3) {
            if (t < 48)
                *(float4*)&xt[4 * t] = *(const float4*)&Xb[(size_t)cbase * 3 + 4 * t];
            if (t >= 64 && t < 128)
                sqt[t - 64] = sq[(size_t)b * NPTS + cbase + (t - 64)];
        } else {
            #pragma unroll
            for (int i = 0; i < 4; ++i)
                *(float4*)&xt[4 * (i * KTHR + t)] =
                    *(const float4*)&Xb[(size_t)cbase * 64 + 4 * (i * KTHR + t)];
            if (t < 64) sqt[t] = sq[(size_t)b * NPTS + cbase + t];
        }
        __syncthreads();

        // ---- score 64 candidates (4 at a time, LDS broadcast reads)
        for (int c0 = 0; c0 < TILE; c0 += 4) {
            float d[4];
            if constexpr (D == 3) {
                #pragma unroll
                for (int cc = 0; cc < 4; ++cc) {
                    const float bx = xt[(c0 + cc) * 3 + 0];
                    const float by = xt[(c0 + cc) * 3 + 1];
                    const float bz = xt[(c0 + cc) * 3 + 2];
                    const float dot = xq[0].x * bx + xq[0].y * by + xq[0].z * bz;
                    d[cc] = sqq + sqt[c0 + cc] - 2.f * dot;
                }
            } else {
                float acc[4] = {0.f, 0.f, 0.f, 0.f};
                #pragma unroll
                for (int k = 0; k < 16; ++k) {
                    const float4 a = xq[k];
                    #pragma unroll
                    for (int cc = 0; cc < 4; ++cc) {
                        const float4 bv = *(const float4*)&xt[(c0 + cc) * 64 + 4 * k];
                        acc[cc] += a.x * bv.x + a.y * bv.y + a.z * bv.z + a.w * bv.w;
                    }
                }
                #pragma unroll
                for (int cc = 0; cc < 4; ++cc)
                    d[cc] = sqq + sqt[c0 + cc] - 2.f * acc[cc];
            }
            const bool h0 = d[0] <= tmax, h1 = d[1] <= tmax,
                       h2 = d[2] <= tmax, h3 = d[3] <= tmax;
            if (h0 | h1 | h2 | h3) {
                #pragma unroll
                for (int cc = 0; cc < 4; ++cc) {
                    if (d[cc] <= tmax) {
                        buf[cnt * KTHR + t] = pack_key(d[cc], cbase + c0 + cc);
                        ++cnt;
                        if (cnt == CAP) flush_buf(lst, buf, t, cnt, tmax);
                    }
                }
            }
        }
        __syncthreads();
    }
    flush_buf(lst, buf, t, cnt, tmax);

    // coalesced partial-list write: part[(split*KNN + k)*BN + b*NPTS + q]
    #pragma unroll
    for (int k = 0; k < KNN; ++k)
        part[((size_t)split * KNN + k) * BN + (size_t)b * NPTS + q] = lst[k];
}

// ---------------------------------------------------------------------------
// merge NSPLIT(=2) sorted 20-lists per query -> final 20 neighbor indices
// ---------------------------------------------------------------------------
__global__ __launch_bounds__(256) void merge_kernel(const u64* __restrict__ part,
                                                    int* __restrict__ idx) {
    const int bq = blockIdx.x * 256 + threadIdx.x;
    const size_t BN = (size_t)BATCH * NPTS;
    int p0 = 0, p1 = 0;
    int* outp = idx + (size_t)bq * KNN;
    for (int k = 0; k < KNN; ++k) {
        const u64 h0 = part[(0 * KNN + p0) * BN + bq];
        const u64 h1 = part[(1 * KNN + p1) * BN + bq];
        const u64 m = (h0 < h1) ? h0 : h1;
        outp[k] = (int)(unsigned)(m & 0xffffffffu);
        if (m == h0) ++p0; else ++p1;
    }
}

// ---------------------------------------------------------------------------
// per-point u = X @ W1b, c = X @ W1a - u + b1
//   Factorization: h1(i,j) = lrelu([x_i | x_j-x_i] @ W1 + b1) = lrelu(c_i + u_j)
// ---------------------------------------------------------------------------
template<int D>
__global__ __launch_bounds__(256) void uc_kernel(
    const float* __restrict__ X, const float* __restrict__ W1,
    const float* __restrict__ b1, float* __restrict__ u, float* __restrict__ cvec) {
    __shared__ float Xs[16 * D];
    const int n0 = blockIdx.x * 16;
    const int t = threadIdx.x;
    for (int i = t; i < 16 * D; i += 256)
        Xs[i] = X[(size_t)n0 * D + i];
    __syncthreads();

    const int o = t & 63;
    const int pg = t >> 6;
    float va[4] = {0.f, 0.f, 0.f, 0.f};
    float vb[4] = {0.f, 0.f, 0.f, 0.f};
    for (int d = 0; d < D; ++d) {
        const float wa = W1[d * 64 + o];
        const float wb = W1[(D + d) * 64 + o];
        #pragma unroll
        for (int pi = 0; pi < 4; ++pi) {
            const float x = Xs[(pg * 4 + pi) * D + d];
            va[pi] += x * wa;
            vb[pi] += x * wb;
        }
    }
    const float bo = b1[o];
    #pragma unroll
    for (int pi = 0; pi < 4; ++pi) {
        const size_t n = (size_t)n0 + pg * 4 + pi;
        u[n * 64 + o] = vb[pi];
        cvec[n * 64 + o] = va[pi] - vb[pi] + bo;
    }
}

// ---------------------------------------------------------------------------
// fused edge MLP + max aggregation (single h buffer; acc lives in regs
// across the barrier, h2 written back into h1s; W3 staged after GEMM1)
// ---------------------------------------------------------------------------
__device__ __forceinline__ void gemm_acc(const float* __restrict__ Xs,
                                         const float* __restrict__ Ws,
                                         const float* __restrict__ bias,
                                         float (&acc)[5][4], const int t) {
    const int rg = t >> 4, og = t & 15;
    #pragma unroll
    for (int oc = 0; oc < 4; ++oc) {
        const float bb = bias[4 * og + oc];
        #pragma unroll
        for (int rr = 0; rr < 5; ++rr) acc[rr][oc] = bb;
    }
    #pragma unroll
    for (int k4 = 0; k4 < 16; ++k4) {
        float4 xv[5];
        #pragma unroll
        for (int rr = 0; rr < 5; ++rr)
            xv[rr] = *(const float4*)&Xs[(5 * rg + rr) * 68 + 4 * k4];
        float4 wv[4];
        #pragma unroll
        for (int kk = 0; kk < 4; ++kk)
            wv[kk] = *(const float4*)&Ws[(4 * k4 + kk) * 64 + 4 * og];
        #pragma unroll
        for (int rr = 0; rr < 5; ++rr) {
            acc[rr][0] += xv[rr].x * wv[0].x + xv[rr].y * wv[1].x + xv[rr].z * wv[2].x + xv[rr].w * wv[3].x;
            acc[rr][1] += xv[rr].x * wv[0].y + xv[rr].y * wv[1].y + xv[rr].z * wv[2].y + xv[rr].w * wv[3].y;
            acc[rr][2] += xv[rr].x * wv[0].z + xv[rr].y * wv[1].z + xv[rr].z * wv[2].z + xv[rr].w * wv[3].z;
            acc[rr][3] += xv[rr].x * wv[0].w + xv[rr].y * wv[1].w + xv[rr].z * wv[2].w + xv[rr].w * wv[3].w;
        }
    }
}

__global__ __launch_bounds__(256) void edge_kernel(
    const float* __restrict__ u, const float* __restrict__ cvec,
    const int* __restrict__ knn_idx,
    const float* __restrict__ W2, const float* __restrict__ b2,
    const float* __restrict__ W3, const float* __restrict__ b3,
    float* __restrict__ out) {
    __shared__ alignas(16) float h1s[80 * 68];
    __shared__ alignas(16) float Ws[64 * 64];
    __shared__ float cs[256];
    __shared__ float mxs[16 * 64];
    __shared__ int idxs[80];

    const int t = threadIdx.x;
    const int p0 = blockIdx.x * 4;
    const int b = p0 >> 12;

    cs[t] = cvec[(size_t)p0 * 64 + t];
    if (t < 80) idxs[t] = knn_idx[(size_t)p0 * KNN + t];
    for (int i = t; i < 4096; i += 256) Ws[i] = W2[i];
    __syncthreads();

    {   // h1 = lrelu(c_i + u_j)
        const int wave = t >> 6, lane = t & 63;
        for (int e = wave; e < 80; e += 4) {
            const int j = idxs[e];
            const float val = u[((size_t)(b << 12) + j) * 64 + lane];
            const float pre = cs[(e / 20) * 64 + lane] + val;
            h1s[e * 68 + lane] = (pre > 0.f) ? pre : SLOPE * pre;
        }
    }
    __syncthreads();

    float acc[5][4];
    gemm_acc(h1s, Ws, b2, acc, t);      // GEMM1: all reads of h1s/Ws
    __syncthreads();

    {   // write h2 back into h1s; stage W3
        const int rg = t >> 4, og = t & 15;
        #pragma unroll
        for (int rr = 0; rr < 5; ++rr)
            #pragma unroll
            for (int oc = 0; oc < 4; ++oc) {
                float v = acc[rr][oc];
                v = (v > 0.f) ? v : SLOPE * v;
                h1s[(5 * rg + rr) * 68 + 4 * og + oc] = v;
            }
        for (int i = t; i < 4096; i += 256) Ws[i] = W3[i];
    }
    __syncthreads();

    gemm_acc(h1s, Ws, b3, acc, t);      // GEMM2
    {   // max over each thread's 5 rows (within one point: 20 % 5 == 0)
        const int rg = t >> 4, og = t & 15;
        #pragma unroll
        for (int oc = 0; oc < 4; ++oc) {
            float m = -1e30f;
            #pragma unroll
            for (int rr = 0; rr < 5; ++rr) {
                float v = acc[rr][oc];
                v = (v > 0.f) ? v : SLOPE * v;
                m = fmaxf(m, v);
            }
            mxs[rg * 64 + 4 * og + oc] = m;
        }
    }
    __syncthreads();

    const int p = t >> 6, col = t & 63;
    const float m = fmaxf(fmaxf(mxs[(4 * p + 0) * 64 + col], mxs[(4 * p + 1) * 64 + col]),
                          fmaxf(mxs[(4 * p + 2) * 64 + col], mxs[(4 * p + 3) * 64 + col]));
    out[(size_t)(p0 + p) * 64 + col] = m;
}

// ---------------------------------------------------------------------------
extern "C" void kernel_launch(void* const* d_in, const int* in_sizes, int n_in,
                              void* d_out, int out_size, void* d_ws, size_t ws_size,
                              hipStream_t stream) {
    const float* pos = (const float*)d_in[0];
    const float* w11 = (const float*)d_in[1];  const float* b11 = (const float*)d_in[2];
    const float* w12 = (const float*)d_in[3];  const float* b12 = (const float*)d_in[4];
    const float* w13 = (const float*)d_in[5];  const float* b13 = (const float*)d_in[6];
    const float* w21 = (const float*)d_in[7];  const float* b21 = (const float*)d_in[8];
    const float* w22 = (const float*)d_in[9];  const float* b22 = (const float*)d_in[10];
    const float* w23 = (const float*)d_in[11]; const float* b23 = (const float*)d_in[12];
    const float* w31 = (const float*)d_in[13]; const float* b31 = (const float*)d_in[14];
    const float* w32 = (const float*)d_in[15]; const float* b32 = (const float*)d_in[16];
    const float* w33 = (const float*)d_in[17]; const float* b33 = (const float*)d_in[18];

    const int BN = BATCH * NPTS;   // 32768
    // Workspace layout (36.3 MB total -- identical footprint to the R1-proven
    // layout). part (NSPLIT*KNN*BN u64 = 10.5 MB) aliases ubuf/cbuf (16.8 MB):
    // per EdgeConv, knn2 writes part (ubuf/cbuf dead), merge drains it into
    // idx, THEN uc overwrites ubuf/cbuf. knn2 inputs pos/x1/x2/sqb are all
    // disjoint from the part region.
    float* ws = (float*)d_ws;
    float* x1   = ws;                          // [BN][64]
    float* x2   = x1 + (size_t)BN * 64;        // [BN][64]
    float* sqb  = x2 + (size_t)BN * 64;        // [BN]
    int*   idx  = (int*)(sqb + BN);            // [BN][20]
    float* ubuf = (float*)(idx + (size_t)BN * KNN);   // [BN][64]
    float* cbuf = ubuf + (size_t)BN * 64;      // [BN][64]
    u64* part = (u64*)ubuf;                    // [NSPLIT][KNN][BN] (10.5 MB)

    const dim3 knn_grid(NPTS / KTHR, NSPLIT, BATCH);

    // ---- EdgeConv 1 (D=3)
    sq_kernel<3><<<BN / 256, 256, 0, stream>>>(pos, sqb);
    knn2_kernel<3><<<knn_grid, KTHR, 0, stream>>>(pos, sqb, part);
    merge_kernel<<<BN / 256, 256, 0, stream>>>(part, idx);
    uc_kernel<3><<<BN / 16, 256, 0, stream>>>(pos, w11, b11, ubuf, cbuf);
    edge_kernel<<<BN / 4, 256, 0, stream>>>(ubuf, cbuf, idx, w12, b12, w13, b13, x1);

    // ---- EdgeConv 2 (D=64)
    sq_kernel<64><<<BN / 256, 256, 0, stream>>>(x1, sqb);
    knn2_kernel<64><<<knn_grid, KTHR, 0, stream>>>(x1, sqb, part);
    merge_kernel<<<BN / 256, 256, 0, stream>>>(part, idx);
    uc_kernel<64><<<BN / 16, 256, 0, stream>>>(x1, w21, b21, ubuf, cbuf);
    edge_kernel<<<BN / 4, 256, 0, stream>>>(ubuf, cbuf, idx, w22, b22, w23, b23, x2);

    // ---- EdgeConv 3 (D=64)
    sq_kernel<64><<<BN / 256, 256, 0, stream>>>(x2, sqb);
    knn2_kernel<64><<<knn_grid, KTHR, 0, stream>>>(x2, sqb, part);
    merge_kernel<<<BN / 256, 256, 0, stream>>>(part, idx);
    uc_kernel<64><<<BN / 16, 256, 0, stream>>>(x2, w31, b31, ubuf, cbuf);
    edge_kernel<<<BN / 4, 256, 0, stream>>>(ubuf, cbuf, idx, w32, b32, w33, b33, (float*)d_out);
}

// Round 4
// 3891.066 us; speedup vs baseline: 3.0247x; 3.0247x over previous
//
#include <hip/hip_runtime.h>
#include <stdint.h>

#define BATCH 8
#define NPTS 4096
#define KNN 20
#define NSPLIT 4
#define CAND_PER_SPLIT (NPTS / NSPLIT)   // 1024
#define TILE 64
#define CAP 16                            // flush trigger
#define CAPMAX 20                         // buffer capacity (CAP + 4 slack)
#define KTHR 128                          // knn2 block size
constexpr float SLOPE = 0.2f;

typedef unsigned long long u64;
// hi word unpacks to FLT_MAX (0x7F7FFFFF) -- FINITE, so the tmax threshold
// stays permissive (not NaN!) until the list holds 20 real entries.
#define INIT_KEY 0xFF7FFFFFFFFFFFFFULL

// ---------------------------------------------------------------------------
// squared norms
// ---------------------------------------------------------------------------
template<int D>
__global__ __launch_bounds__(256) void sq_kernel(const float* __restrict__ X,
                                                 float* __restrict__ sq) {
    const int i = blockIdx.x * 256 + threadIdx.x;
    if constexpr (D == 3) {
        const float* p = X + (size_t)i * 3;
        float s = 0.f;
        s += p[0] * p[0]; s += p[1] * p[1]; s += p[2] * p[2];
        sq[i] = s;
    } else {
        const float4* p = (const float4*)(X + (size_t)i * 64);
        float s = 0.f;
        #pragma unroll
        for (int k = 0; k < 16; ++k) {
            float4 v = p[k];
            s += v.x * v.x; s += v.y * v.y; s += v.z * v.z; s += v.w * v.w;
        }
        sq[i] = s;
    }
}

// ---------------------------------------------------------------------------
// kNN: query-per-thread, LDS-broadcast candidate tiles, threshold+buffer
// selection (exact top-20 on packed (d,j) u64 keys, ties -> low j).
// Flushes are WAVE-UNIFORM (__any) so the expensive insert chain runs
// ~10x/split instead of ~384x with sparse exec masks.
// grid: (NPTS/KTHR, NSPLIT, BATCH), KTHR threads.
// ---------------------------------------------------------------------------
__device__ __forceinline__ u64 pack_key(float d, int j) {
    unsigned ub = __float_as_uint(d);
    ub = (ub & 0x80000000u) ? ~ub : (ub | 0x80000000u);
    return ((u64)ub << 32) | (unsigned)j;
}
__device__ __forceinline__ float key_hi_to_d(unsigned hi) {
    unsigned u = (hi & 0x80000000u) ? (hi ^ 0x80000000u) : ~hi;
    return __uint_as_float(u);
}
__device__ __forceinline__ void insert_key(u64 (&lst)[KNN], u64 c) {
    #pragma unroll
    for (int k = 0; k < KNN; ++k) {
        const u64 lo = (lst[k] < c) ? lst[k] : c;
        const u64 hi = (lst[k] < c) ? c : lst[k];
        lst[k] = lo; c = hi;
    }
}
__device__ __forceinline__ void flush_buf(u64 (&lst)[KNN], const u64* __restrict__ buf,
                                          int t, int& cnt, float& tmax) {
    for (int i = 0; i < CAPMAX; ++i) {
        if (i < cnt) {
            const u64 key = buf[i * KTHR + t];
            if (key < lst[KNN - 1]) insert_key(lst, key);
        }
    }
    cnt = 0;
    tmax = key_hi_to_d((unsigned)(lst[KNN - 1] >> 32));
}

template<int D>   // 3 or 64
__global__ __launch_bounds__(KTHR) void knn2_kernel(
    const float* __restrict__ X, const float* __restrict__ sq,
    u64* __restrict__ part)      // [NSPLIT][KNN][B*N]
{
    __shared__ alignas(16) float xt[TILE * ((D == 3) ? 3 : 64)];
    __shared__ float sqt[TILE];
    __shared__ u64 buf[CAPMAX * KTHR];     // lane-interleaved: buf[i][t]

    const int t = threadIdx.x;
    const int split = blockIdx.y, b = blockIdx.z;
    const int q = blockIdx.x * KTHR + t;
    const float* Xb = X + (size_t)b * NPTS * D;
    const size_t BN = (size_t)BATCH * NPTS;

    float4 xq[(D == 3) ? 1 : 16];
    if constexpr (D == 3) {
        const float* qp = Xb + (size_t)q * 3;
        xq[0].x = qp[0]; xq[0].y = qp[1]; xq[0].z = qp[2]; xq[0].w = 0.f;
    } else {
        #pragma unroll
        for (int k = 0; k < 16; ++k)
            xq[k] = *(const float4*)&Xb[(size_t)q * 64 + 4 * k];
    }
    const float sqq = sq[(size_t)b * NPTS + q];

    u64 lst[KNN];
    #pragma unroll
    for (int k = 0; k < KNN; ++k) lst[k] = INIT_KEY;
    float tmax = 3.402823466e38f;   // FLT_MAX: pass everything until list full
    int cnt = 0;

    for (int tile = 0; tile < CAND_PER_SPLIT / TILE; ++tile) {
        const int cbase = split * CAND_PER_SPLIT + tile * TILE;
        // ---- stage candidate tile
        if constexpr (D == 3) {
            if (t < 48)
                *(float4*)&xt[4 * t] = *(const float4*)&Xb[(size_t)cbase * 3 + 4 * t];
            if (t >= 64 && t < 128)
                sqt[t - 64] = sq[(size_t)b * NPTS + cbase + (t - 64)];
        } else {
            #pragma unroll
            for (int i = 0; i < 8; ++i)
                *(float4*)&xt[4 * (i * KTHR + t)] =
                    *(const float4*)&Xb[(size_t)cbase * 64 + 4 * (i * KTHR + t)];
            if (t < 64) sqt[t] = sq[(size_t)b * NPTS + cbase + t];
        }
        __syncthreads();

        // ---- score 64 candidates (4 at a time, LDS broadcast reads)
        for (int c0 = 0; c0 < TILE; c0 += 4) {
            float d[4];
            if constexpr (D == 3) {
                #pragma unroll
                for (int cc = 0; cc < 4; ++cc) {
                    const float bx = xt[(c0 + cc) * 3 + 0];
                    const float by = xt[(c0 + cc) * 3 + 1];
                    const float bz = xt[(c0 + cc) * 3 + 2];
                    const float dot = xq[0].x * bx + xq[0].y * by + xq[0].z * bz;
                    d[cc] = sqq + sqt[c0 + cc] - 2.f * dot;
                }
            } else {
                float acc[4] = {0.f, 0.f, 0.f, 0.f};
                #pragma unroll
                for (int k = 0; k < 16; ++k) {
                    const float4 a = xq[k];
                    #pragma unroll
                    for (int cc = 0; cc < 4; ++cc) {
                        const float4 bv = *(const float4*)&xt[(c0 + cc) * 64 + 4 * k];
                        acc[cc] += a.x * bv.x + a.y * bv.y + a.z * bv.z + a.w * bv.w;
                    }
                }
                #pragma unroll
                for (int cc = 0; cc < 4; ++cc)
                    d[cc] = sqq + sqt[c0 + cc] - 2.f * acc[cc];
            }
            const bool h0 = d[0] <= tmax, h1 = d[1] <= tmax,
                       h2 = d[2] <= tmax, h3 = d[3] <= tmax;
            if (h0 | h1 | h2 | h3) {
                #pragma unroll
                for (int cc = 0; cc < 4; ++cc) {
                    if (d[cc] <= tmax) {
                        buf[cnt * KTHR + t] = pack_key(d[cc], cbase + c0 + cc);
                        ++cnt;
                    }
                }
            }
            // wave-uniform flush: max 4 appends since last check, so cnt <= 19
            if (__any(cnt >= CAP)) flush_buf(lst, buf, t, cnt, tmax);
        }
        __syncthreads();
    }
    if (__any(cnt > 0)) flush_buf(lst, buf, t, cnt, tmax);

    // coalesced partial-list write: part[(split*KNN + k)*BN + b*NPTS + q]
    #pragma unroll
    for (int k = 0; k < KNN; ++k)
        part[((size_t)split * KNN + k) * BN + (size_t)b * NPTS + q] = lst[k];
}

// ---------------------------------------------------------------------------
// merge NSPLIT(=4) sorted 20-lists per query -> final 20 neighbor indices
// ---------------------------------------------------------------------------
__global__ __launch_bounds__(256) void merge_kernel(const u64* __restrict__ part,
                                                    int* __restrict__ idx) {
    const int bq = blockIdx.x * 256 + threadIdx.x;
    const size_t BN = (size_t)BATCH * NPTS;
    int p0 = 0, p1 = 0, p2 = 0, p3 = 0;
    int* outp = idx + (size_t)bq * KNN;
    for (int k = 0; k < KNN; ++k) {
        const u64 h0 = part[(0 * KNN + p0) * BN + bq];
        const u64 h1 = part[(1 * KNN + p1) * BN + bq];
        const u64 h2 = part[(2 * KNN + p2) * BN + bq];
        const u64 h3 = part[(3 * KNN + p3) * BN + bq];
        const u64 m01 = (h0 < h1) ? h0 : h1;
        const u64 m23 = (h2 < h3) ? h2 : h3;
        const u64 m = (m01 < m23) ? m01 : m23;
        outp[k] = (int)(unsigned)(m & 0xffffffffu);
        if (m == h0) ++p0; else if (m == h1) ++p1; else if (m == h2) ++p2; else ++p3;
    }
}

// ---------------------------------------------------------------------------
// per-point u = X @ W1b, c = X @ W1a - u + b1
//   Factorization: h1(i,j) = lrelu([x_i | x_j-x_i] @ W1 + b1) = lrelu(c_i + u_j)
// ---------------------------------------------------------------------------
template<int D>
__global__ __launch_bounds__(256) void uc_kernel(
    const float* __restrict__ X, const float* __restrict__ W1,
    const float* __restrict__ b1, float* __restrict__ u, float* __restrict__ cvec) {
    __shared__ float Xs[16 * D];
    const int n0 = blockIdx.x * 16;
    const int t = threadIdx.x;
    for (int i = t; i < 16 * D; i += 256)
        Xs[i] = X[(size_t)n0 * D + i];
    __syncthreads();

    const int o = t & 63;
    const int pg = t >> 6;
    float va[4] = {0.f, 0.f, 0.f, 0.f};
    float vb[4] = {0.f, 0.f, 0.f, 0.f};
    for (int d = 0; d < D; ++d) {
        const float wa = W1[d * 64 + o];
        const float wb = W1[(D + d) * 64 + o];
        #pragma unroll
        for (int pi = 0; pi < 4; ++pi) {
            const float x = Xs[(pg * 4 + pi) * D + d];
            va[pi] += x * wa;
            vb[pi] += x * wb;
        }
    }
    const float bo = b1[o];
    #pragma unroll
    for (int pi = 0; pi < 4; ++pi) {
        const size_t n = (size_t)n0 + pg * 4 + pi;
        u[n * 64 + o] = vb[pi];
        cvec[n * 64 + o] = va[pi] - vb[pi] + bo;
    }
}

// ---------------------------------------------------------------------------
// fused edge MLP + max aggregation (single h buffer; acc lives in regs
// across the barrier, h2 written back into h1s; W3 staged after GEMM1)
// ---------------------------------------------------------------------------
__device__ __forceinline__ void gemm_acc(const float* __restrict__ Xs,
                                         const float* __restrict__ Ws,
                                         const float* __restrict__ bias,
                                         float (&acc)[5][4], const int t) {
    const int rg = t >> 4, og = t & 15;
    #pragma unroll
    for (int oc = 0; oc < 4; ++oc) {
        const float bb = bias[4 * og + oc];
        #pragma unroll
        for (int rr = 0; rr < 5; ++rr) acc[rr][oc] = bb;
    }
    #pragma unroll
    for (int k4 = 0; k4 < 16; ++k4) {
        float4 xv[5];
        #pragma unroll
        for (int rr = 0; rr < 5; ++rr)
            xv[rr] = *(const float4*)&Xs[(5 * rg + rr) * 68 + 4 * k4];
        float4 wv[4];
        #pragma unroll
        for (int kk = 0; kk < 4; ++kk)
            wv[kk] = *(const float4*)&Ws[(4 * k4 + kk) * 64 + 4 * og];
        #pragma unroll
        for (int rr = 0; rr < 5; ++rr) {
            acc[rr][0] += xv[rr].x * wv[0].x + xv[rr].y * wv[1].x + xv[rr].z * wv[2].x + xv[rr].w * wv[3].x;
            acc[rr][1] += xv[rr].x * wv[0].y + xv[rr].y * wv[1].y + xv[rr].z * wv[2].y + xv[rr].w * wv[3].y;
            acc[rr][2] += xv[rr].x * wv[0].z + xv[rr].y * wv[1].z + xv[rr].z * wv[2].z + xv[rr].w * wv[3].z;
            acc[rr][3] += xv[rr].x * wv[0].w + xv[rr].y * wv[1].w + xv[rr].z * wv[2].w + xv[rr].w * wv[3].w;
        }
    }
}

__global__ __launch_bounds__(256) void edge_kernel(
    const float* __restrict__ u, const float* __restrict__ cvec,
    const int* __restrict__ knn_idx,
    const float* __restrict__ W2, const float* __restrict__ b2,
    const float* __restrict__ W3, const float* __restrict__ b3,
    float* __restrict__ out) {
    __shared__ alignas(16) float h1s[80 * 68];
    __shared__ alignas(16) float Ws[64 * 64];
    __shared__ float cs[256];
    __shared__ float mxs[16 * 64];
    __shared__ int idxs[80];

    const int t = threadIdx.x;
    const int p0 = blockIdx.x * 4;
    const int b = p0 >> 12;

    cs[t] = cvec[(size_t)p0 * 64 + t];
    if (t < 80) idxs[t] = knn_idx[(size_t)p0 * KNN + t];
    for (int i = t; i < 4096; i += 256) Ws[i] = W2[i];
    __syncthreads();

    {   // h1 = lrelu(c_i + u_j)
        const int wave = t >> 6, lane = t & 63;
        for (int e = wave; e < 80; e += 4) {
            const int j = idxs[e];
            const float val = u[((size_t)(b << 12) + j) * 64 + lane];
            const float pre = cs[(e / 20) * 64 + lane] + val;
            h1s[e * 68 + lane] = (pre > 0.f) ? pre : SLOPE * pre;
        }
    }
    __syncthreads();

    float acc[5][4];
    gemm_acc(h1s, Ws, b2, acc, t);      // GEMM1: all reads of h1s/Ws
    __syncthreads();

    {   // write h2 back into h1s; stage W3
        const int rg = t >> 4, og = t & 15;
        #pragma unroll
        for (int rr = 0; rr < 5; ++rr)
            #pragma unroll
            for (int oc = 0; oc < 4; ++oc) {
                float v = acc[rr][oc];
                v = (v > 0.f) ? v : SLOPE * v;
                h1s[(5 * rg + rr) * 68 + 4 * og + oc] = v;
            }
        for (int i = t; i < 4096; i += 256) Ws[i] = W3[i];
    }
    __syncthreads();

    gemm_acc(h1s, Ws, b3, acc, t);      // GEMM2
    {   // max over each thread's 5 rows (within one point: 20 % 5 == 0)
        const int rg = t >> 4, og = t & 15;
        #pragma unroll
        for (int oc = 0; oc < 4; ++oc) {
            float m = -1e30f;
            #pragma unroll
            for (int rr = 0; rr < 5; ++rr) {
                float v = acc[rr][oc];
                v = (v > 0.f) ? v : SLOPE * v;
                m = fmaxf(m, v);
            }
            mxs[rg * 64 + 4 * og + oc] = m;
        }
    }
    __syncthreads();

    const int p = t >> 6, col = t & 63;
    const float m = fmaxf(fmaxf(mxs[(4 * p + 0) * 64 + col], mxs[(4 * p + 1) * 64 + col]),
                          fmaxf(mxs[(4 * p + 2) * 64 + col], mxs[(4 * p + 3) * 64 + col]));
    out[(size_t)(p0 + p) * 64 + col] = m;
}

// ---------------------------------------------------------------------------
extern "C" void kernel_launch(void* const* d_in, const int* in_sizes, int n_in,
                              void* d_out, int out_size, void* d_ws, size_t ws_size,
                              hipStream_t stream) {
    const float* pos = (const float*)d_in[0];
    const float* w11 = (const float*)d_in[1];  const float* b11 = (const float*)d_in[2];
    const float* w12 = (const float*)d_in[3];  const float* b12 = (const float*)d_in[4];
    const float* w13 = (const float*)d_in[5];  const float* b13 = (const float*)d_in[6];
    const float* w21 = (const float*)d_in[7];  const float* b21 = (const float*)d_in[8];
    const float* w22 = (const float*)d_in[9];  const float* b22 = (const float*)d_in[10];
    const float* w23 = (const float*)d_in[11]; const float* b23 = (const float*)d_in[12];
    const float* w31 = (const float*)d_in[13]; const float* b31 = (const float*)d_in[14];
    const float* w32 = (const float*)d_in[15]; const float* b32 = (const float*)d_in[16];
    const float* w33 = (const float*)d_in[17]; const float* b33 = (const float*)d_in[18];

    const int BN = BATCH * NPTS;   // 32768
    // Workspace layout: [sqb][idx][x1][u][c][x2], 34.6 MB total.
    // part = NSPLIT*KNN*BN u64 = 21.0 MB, aliased per-conv onto DEAD buffers:
    //   conv1: part at x1 (spans x1,u,c = 24 MB; all dead, input is pos)
    //   conv2: part at u  (spans u,c,x2 = 24 MB; x1 is the live input)
    //   conv3: part at x1 (spans x1,u,c = 24 MB; x2 is the live input)
    // Sequence per conv: knn2 writes part -> merge drains part into idx ->
    // uc overwrites u,c -> edge writes x1/x2/out.  No overlap of live data.
    float* ws = (float*)d_ws;
    float* sqb = ws;                                  // [BN]
    int*   idx = (int*)(sqb + BN);                    // [BN][20]
    float* x1  = (float*)(idx + (size_t)BN * KNN);    // [BN][64]
    float* ubuf = x1 + (size_t)BN * 64;               // [BN][64]
    float* cbuf = ubuf + (size_t)BN * 64;             // [BN][64]
    float* x2  = cbuf + (size_t)BN * 64;              // [BN][64]
    u64* part13 = (u64*)x1;                           // conv1/conv3 partials
    u64* part2  = (u64*)ubuf;                         // conv2 partials

    const dim3 knn_grid(NPTS / KTHR, NSPLIT, BATCH);

    // ---- EdgeConv 1 (D=3)
    sq_kernel<3><<<BN / 256, 256, 0, stream>>>(pos, sqb);
    knn2_kernel<3><<<knn_grid, KTHR, 0, stream>>>(pos, sqb, part13);
    merge_kernel<<<BN / 256, 256, 0, stream>>>(part13, idx);
    uc_kernel<3><<<BN / 16, 256, 0, stream>>>(pos, w11, b11, ubuf, cbuf);
    edge_kernel<<<BN / 4, 256, 0, stream>>>(ubuf, cbuf, idx, w12, b12, w13, b13, x1);

    // ---- EdgeConv 2 (D=64)
    sq_kernel<64><<<BN / 256, 256, 0, stream>>>(x1, sqb);
    knn2_kernel<64><<<knn_grid, KTHR, 0, stream>>>(x1, sqb, part2);
    merge_kernel<<<BN / 256, 256, 0, stream>>>(part2, idx);
    uc_kernel<64><<<BN / 16, 256, 0, stream>>>(x1, w21, b21, ubuf, cbuf);
    edge_kernel<<<BN / 4, 256, 0, stream>>>(ubuf, cbuf, idx, w22, b22, w23, b23, x2);

    // ---- EdgeConv 3 (D=64)
    sq_kernel<64><<<BN / 256, 256, 0, stream>>>(x2, sqb);
    knn2_kernel<64><<<knn_grid, KTHR, 0, stream>>>(x2, sqb, part13);
    merge_kernel<<<BN / 256, 256, 0, stream>>>(part13, idx);
    uc_kernel<64><<<BN / 16, 256, 0, stream>>>(x2, w31, b31, ubuf, cbuf);
    edge_kernel<<<BN / 4, 256, 0, stream>>>(ubuf, cbuf, idx, w32, b32, w33, b33, (float*)d_out);
}